// Round 3
// baseline (272.681 us; speedup 1.0000x reference)
//
#include <hip/hip_runtime.h>

// LinearAttention MI355X: B=2, C=96, N=131072 (x stored [B,C,N]), 8 heads x 12.
// Persistent-block fp16-MFMA pipeline; weights/M held as register fragments.
//
// Fragment layouts (gfx950, verified by round-2 pass):
//   A[m=lane&15][k=quad*8+j], B[k=quad*8+j][col=lane&15], C/D row=quad*4+reg col=lane&15

typedef _Float16 half_t;
typedef _Float16 half4v __attribute__((ext_vector_type(4)));
typedef _Float16 half8  __attribute__((ext_vector_type(8)));
typedef float    f32x4  __attribute__((ext_vector_type(4)));

#define MFMA16 __builtin_amdgcn_mfma_f32_16x16x32_f16
#define NSH 17
#define NP 16

// ---------------- pass 1: k,v GEMMs + context + S ----------------
__global__ __launch_bounds__(256, 2)
void p1(const float* __restrict__ x, const float* __restrict__ Wk,
        const float* __restrict__ Wv, float* __restrict__ part) {
  __shared__ __align__(16) char smem[79392];
  half_t* xs = (half_t*)smem;                // [128][104]  x tile, [token][c]
  half_t* ke = (half_t*)(smem + 26624);      // [97][136]   exp(k logits), [c][token]
  half_t* vl = (half_t*)(smem + 53008);      // [97][136]   v logits,      [c][token]

  const int tid  = threadIdx.x;
  const int lane = tid & 63, l15 = lane & 15, quad = lane >> 4, wid = tid >> 6;
  const int w0 = wid & 1, w1 = wid >> 1;     // token-half / cout-half split
  const int b  = blockIdx.x >> 8;
  const int n0 = (blockIdx.x & 255) << 9;    // 512 tokens per block
  const float* xb = x + (((size_t)b * 96) << NSH);

  // Wk/Wv B-operand fragments in registers: B[k=c][col=cout]
  half8 wkB[3][3], wvB[3][3];
#pragma unroll
  for (int ct = 0; ct < 3; ++ct)
#pragma unroll
    for (int ks = 0; ks < 3; ++ks) {
      const int row = 48 * w1 + ct * 16 + l15;
      const float* pk = Wk + row * 96 + ks * 32 + quad * 8;
      const float* pv = Wv + row * 96 + ks * 32 + quad * 8;
      half8 hk, hv;
#pragma unroll
      for (int j = 0; j < 8; ++j) { hk[j] = (half_t)pk[j]; hv[j] = (half_t)pv[j]; }
      wkB[ct][ks] = hk; wvB[ct][ks] = hv;
    }

  const int sn = tid & 127, scg = tid >> 7;  // staging: token, c-half
  { // prologue: stage tile 0
    float xr[48];
#pragma unroll
    for (int i = 0; i < 48; ++i)
      xr[i] = xb[(((size_t)(scg * 48 + i)) << NSH) + n0 + sn];
#pragma unroll
    for (int j = 0; j < 12; ++j) {
      half4v h;
#pragma unroll
      for (int e = 0; e < 4; ++e) h[e] = (half_t)xr[4 * j + e];
      *(half4v*)&xs[sn * 104 + scg * 48 + 4 * j] = h;
    }
  }
  f32x4 ctxa[2] = {{0.f,0.f,0.f,0.f},{0.f,0.f,0.f,0.f}};
  float sacc = 0.f;
  __syncthreads();

  for (int t = 0; t < 4; ++t) {
    float xr[48];
    if (t < 3) {  // prefetch next tile into VGPRs (consumed after the GEMMs)
#pragma unroll
      for (int i = 0; i < 48; ++i)
        xr[i] = xb[(((size_t)(scg * 48 + i)) << NSH) + n0 + (t + 1) * 128 + sn];
    }
    f32x4 acc[4][3];
    // ---- k GEMM: D[token][cout], A = xs rows (tokens), B = Wk regs ----
#pragma unroll
    for (int rt = 0; rt < 4; ++rt)
#pragma unroll
      for (int ct = 0; ct < 3; ++ct) acc[rt][ct] = (f32x4){0.f,0.f,0.f,0.f};
#pragma unroll
    for (int ks = 0; ks < 3; ++ks) {
      half8 af[4];
#pragma unroll
      for (int rt = 0; rt < 4; ++rt)
        af[rt] = *(const half8*)&xs[(64 * w0 + rt * 16 + l15) * 104 + ks * 32 + quad * 8];
#pragma unroll
      for (int rt = 0; rt < 4; ++rt)
#pragma unroll
        for (int ct = 0; ct < 3; ++ct)
          acc[rt][ct] = MFMA16(af[rt], wkB[ct][ks], acc[rt][ct], 0, 0, 0);
    }
    // epilogue: ke[cout][token], 4 consecutive tokens per lane -> b64
#pragma unroll
    for (int rt = 0; rt < 4; ++rt)
#pragma unroll
      for (int ct = 0; ct < 3; ++ct) {
        half4v h;
#pragma unroll
        for (int i = 0; i < 4; ++i) h[i] = (half_t)__expf(acc[rt][ct][i]);
        *(half4v*)&ke[(48 * w1 + ct * 16 + l15) * 136 + 64 * w0 + rt * 16 + quad * 4] = h;
      }
    // ---- v GEMM ----
#pragma unroll
    for (int rt = 0; rt < 4; ++rt)
#pragma unroll
      for (int ct = 0; ct < 3; ++ct) acc[rt][ct] = (f32x4){0.f,0.f,0.f,0.f};
#pragma unroll
    for (int ks = 0; ks < 3; ++ks) {
      half8 af[4];
#pragma unroll
      for (int rt = 0; rt < 4; ++rt)
        af[rt] = *(const half8*)&xs[(64 * w0 + rt * 16 + l15) * 104 + ks * 32 + quad * 8];
#pragma unroll
      for (int rt = 0; rt < 4; ++rt)
#pragma unroll
        for (int ct = 0; ct < 3; ++ct)
          acc[rt][ct] = MFMA16(af[rt], wvB[ct][ks], acc[rt][ct], 0, 0, 0);
    }
#pragma unroll
    for (int rt = 0; rt < 4; ++rt)
#pragma unroll
      for (int ct = 0; ct < 3; ++ct) {
        half4v h;
#pragma unroll
        for (int i = 0; i < 4; ++i) h[i] = (half_t)acc[rt][ct][i];
        *(half4v*)&vl[(48 * w1 + ct * 16 + l15) * 136 + 64 * w0 + rt * 16 + quad * 4] = h;
      }
    __syncthreads();   // xs reads done; ke/vl now visible to all waves
    if (t < 3) {       // write next x tile (xs free now)
#pragma unroll
      for (int j = 0; j < 12; ++j) {
        half4v h;
#pragma unroll
        for (int e = 0; e < 4; ++e) h[e] = (half_t)xr[4 * j + e];
        *(half4v*)&xs[sn * 104 + scg * 48 + 4 * j] = h;
      }
    }
    // ---- context MFMA over tokens (wave -> heads 2w,2w+1) ----
#pragma unroll
    for (int hh = 0; hh < 2; ++hh) {
      int rr = (wid * 2 + hh) * 12 + l15; rr = rr > 96 ? 96 : rr;  // rows>=96 garbage, discarded
#pragma unroll
      for (int ks = 0; ks < 4; ++ks) {
        half8 a  = *(const half8*)&ke[rr * 136 + ks * 32 + quad * 8];
        half8 bv = *(const half8*)&vl[rr * 136 + ks * 32 + quad * 8];
        ctxa[hh] = MFMA16(a, bv, ctxa[hh], 0, 0, 0);
      }
    }
    // ---- S row sums ----
    if (tid < 192) {
      const int c = tid >> 1, seg = tid & 1;
#pragma unroll
      for (int j = 0; j < 8; ++j) {
        half8 v = *(const half8*)&ke[c * 136 + seg * 64 + j * 8];
#pragma unroll
        for (int e = 0; e < 8; ++e) sacc += (float)v[e];
      }
    }
    __syncthreads();   // ctx/S reads done before next tile's ke/vl/xs writes
  }
  // flush block partials
  float* dst = part + (size_t)((blockIdx.x & (NP - 1)) * 2 + b) * 1248;
#pragma unroll
  for (int hh = 0; hh < 2; ++hh) {
#pragma unroll
    for (int i = 0; i < 4; ++i) {
      const int d = quad * 4 + i, e = l15;
      if (d < 12 && e < 12)
        atomicAdd(&dst[(wid * 2 + hh) * 144 + d * 12 + e], ctxa[hh][i]);
    }
  }
  if (tid < 192) atomicAdd(&dst[1152 + (tid >> 1)], sacc);
}

// ---------------- pass 2: fold Wproj into tiny context ----------------
__global__ void kB(const float* __restrict__ part, const float* __restrict__ Wproj,
                   float* __restrict__ Mt) {
  const int g = blockIdx.x * 256 + threadIdx.x;   // 2*96*96 = 18432 exactly
  const int b = g / (96 * 96);
  const int rem = g % (96 * 96);
  const int o = rem / 96;
  const int r = rem % 96;        // r = h*12+d
  const int h = r / 12, d = r % 12;
  float s = 0.f;
#pragma unroll
  for (int p = 0; p < NP; ++p) s += part[(size_t)(p * 2 + b) * 1248 + 1152 + r];
  float acc = 0.f;
#pragma unroll
  for (int e = 0; e < 12; ++e) {
    float ce = 0.f;
#pragma unroll
    for (int p = 0; p < NP; ++p)
      ce += part[(size_t)(p * 2 + b) * 1248 + h * 144 + d * 12 + e];
    acc = fmaf(ce, Wproj[o * 96 + h * 12 + e], acc);
  }
  Mt[(size_t)(b * 96 + o) * 96 + r] = acc / s;
}

// ---------------- pass 3: q GEMM + softmax + out GEMM ----------------
__global__ __launch_bounds__(256, 2)
void p3(const float* __restrict__ x, const float* __restrict__ Wq,
        const float* __restrict__ Mt, float* __restrict__ out) {
  __shared__ __align__(16) char smem[53248];
  half_t* xs = (half_t*)smem;                // [128][104]  [token][c]
  half_t* qs = (half_t*)(smem + 26624);      // [128][104]  [token][r]

  const int tid  = threadIdx.x;
  const int lane = tid & 63, l15 = lane & 15, quad = lane >> 4, wid = tid >> 6;
  const int w0 = wid & 1, w1 = wid >> 1;
  const int b  = blockIdx.x >> 8;
  const int n0 = (blockIdx.x & 255) << 9;
  const float* xb = x + (((size_t)b * 96) << NSH);

  // Wq A-operand fragments: A[m=r][k=c]
  half8 aw[3][3];
#pragma unroll
  for (int rt = 0; rt < 3; ++rt)
#pragma unroll
    for (int ks = 0; ks < 3; ++ks) {
      const float* pq = Wq + (48 * w0 + rt * 16 + l15) * 96 + ks * 32 + quad * 8;
      half8 h;
#pragma unroll
      for (int j = 0; j < 8; ++j) h[j] = (half_t)pq[j];
      aw[rt][ks] = h;
    }
  // M^T B-operand fragments: B[k=r][col=o] = M[o][r]
  half8 mB[3][3];
  {
    const float* mtb = Mt + (size_t)b * 9216;
#pragma unroll
    for (int ct = 0; ct < 3; ++ct)
#pragma unroll
      for (int ks = 0; ks < 3; ++ks) {
        const float* pm = mtb + (48 * w1 + ct * 16 + l15) * 96 + ks * 32 + quad * 8;
        half8 h;
#pragma unroll
        for (int j = 0; j < 8; ++j) h[j] = (half_t)pm[j];
        mB[ct][ks] = h;
      }
  }

  const int sn = tid & 127, scg = tid >> 7;
  { // prologue: stage tile 0
    float xr[48];
#pragma unroll
    for (int i = 0; i < 48; ++i)
      xr[i] = xb[(((size_t)(scg * 48 + i)) << NSH) + n0 + sn];
#pragma unroll
    for (int j = 0; j < 12; ++j) {
      half4v h;
#pragma unroll
      for (int e = 0; e < 4; ++e) h[e] = (half_t)xr[4 * j + e];
      *(half4v*)&xs[sn * 104 + scg * 48 + 4 * j] = h;
    }
  }
  __syncthreads();

  for (int t = 0; t < 4; ++t) {
    float xr[48];
    if (t < 3) {
#pragma unroll
      for (int i = 0; i < 48; ++i)
        xr[i] = xb[(((size_t)(scg * 48 + i)) << NSH) + n0 + (t + 1) * 128 + sn];
    }
    // ---- q GEMM: D[r][token], A = Wq regs, B = xs ----
    f32x4 qacc[3][4];
#pragma unroll
    for (int rt = 0; rt < 3; ++rt)
#pragma unroll
      for (int ct = 0; ct < 4; ++ct) qacc[rt][ct] = (f32x4){0.f,0.f,0.f,0.f};
#pragma unroll
    for (int ks = 0; ks < 3; ++ks) {
      half8 bf[4];
#pragma unroll
      for (int ct = 0; ct < 4; ++ct)
        bf[ct] = *(const half8*)&xs[(64 * w1 + ct * 16 + l15) * 104 + ks * 32 + quad * 8];
#pragma unroll
      for (int rt = 0; rt < 3; ++rt)
#pragma unroll
        for (int ct = 0; ct < 4; ++ct)
          qacc[rt][ct] = MFMA16(aw[rt][ks], bf[ct], qacc[rt][ct], 0, 0, 0);
    }
    // epilogue -> qs[token][r]: lane's 4 rows (r) contiguous -> b64
#pragma unroll
    for (int rt = 0; rt < 3; ++rt)
#pragma unroll
      for (int ct = 0; ct < 4; ++ct) {
        half4v h;
#pragma unroll
        for (int i = 0; i < 4; ++i) h[i] = (half_t)qacc[rt][ct][i];
        *(half4v*)&qs[(64 * w1 + ct * 16 + l15) * 104 + 48 * w0 + rt * 16 + quad * 4] = h;
      }
    __syncthreads();
    // ---- softmax over each head's 12 dims; also write next x tile ----
    {
      const int n = tid & 127, g = tid >> 7;
      float q[48];
#pragma unroll
      for (int j = 0; j < 12; ++j) {
        half4v v = *(const half4v*)&qs[n * 104 + g * 48 + j * 4];
#pragma unroll
        for (int e = 0; e < 4; ++e) q[j * 4 + e] = (float)v[e];
      }
#pragma unroll
      for (int hh = 0; hh < 4; ++hh) {
        float* ql = q + hh * 12;
        float m = ql[0];
#pragma unroll
        for (int j = 1; j < 12; ++j) m = fmaxf(m, ql[j]);
        float s = 0.f;
#pragma unroll
        for (int j = 0; j < 12; ++j) { ql[j] = __expf(ql[j] - m); s += ql[j]; }
        const float inv = 1.0f / s;
#pragma unroll
        for (int j = 0; j < 12; ++j) ql[j] *= inv;
      }
#pragma unroll
      for (int j = 0; j < 12; ++j) {
        half4v v;
#pragma unroll
        for (int e = 0; e < 4; ++e) v[e] = (half_t)q[j * 4 + e];
        *(half4v*)&qs[n * 104 + g * 48 + j * 4] = v;
      }
    }
    if (t < 3) {
#pragma unroll
      for (int j = 0; j < 12; ++j) {
        half4v h;
#pragma unroll
        for (int e = 0; e < 4; ++e) h[e] = (half_t)xr[4 * j + e];
        *(half4v*)&xs[sn * 104 + scg * 48 + 4 * j] = h;
      }
    }
    __syncthreads();
    // ---- out GEMM: D[token][o], A = qs rows (tokens), B = M^T regs ----
    f32x4 oacc[4][3];
#pragma unroll
    for (int rt = 0; rt < 4; ++rt)
#pragma unroll
      for (int ct = 0; ct < 3; ++ct) oacc[rt][ct] = (f32x4){0.f,0.f,0.f,0.f};
#pragma unroll
    for (int ks = 0; ks < 3; ++ks) {
      half8 af[4];
#pragma unroll
      for (int rt = 0; rt < 4; ++rt)
        af[rt] = *(const half8*)&qs[(64 * w0 + rt * 16 + l15) * 104 + ks * 32 + quad * 8];
#pragma unroll
      for (int rt = 0; rt < 4; ++rt)
#pragma unroll
        for (int ct = 0; ct < 3; ++ct)
          oacc[rt][ct] = MFMA16(af[rt], mB[ct][ks], oacc[rt][ct], 0, 0, 0);
    }
    // store: lane's 4 rows are 4 consecutive tokens -> float4 global stores
#pragma unroll
    for (int rt = 0; rt < 4; ++rt)
#pragma unroll
      for (int ct = 0; ct < 3; ++ct) {
        const int o  = 48 * w1 + ct * 16 + l15;
        const size_t off = (((size_t)(b * 96 + o)) << NSH)
                         + n0 + t * 128 + 64 * w0 + rt * 16 + quad * 4;
        *(f32x4*)&out[off] = oacc[rt][ct];
      }
    __syncthreads();   // qs reads done before next tile's qs writes
  }
}

extern "C" void kernel_launch(void* const* d_in, const int* in_sizes, int n_in,
                              void* d_out, int out_size, void* d_ws, size_t ws_size,
                              hipStream_t stream) {
  const float* x     = (const float*)d_in[0];
  const float* Wq    = (const float*)d_in[1];
  const float* Wk    = (const float*)d_in[2];
  const float* Wv    = (const float*)d_in[3];
  const float* Wproj = (const float*)d_in[4];
  float* out = (float*)d_out;
  float* ws  = (float*)d_ws;

  float* part = ws;                      // NP*2*1248 floats
  float* Mt   = ws + NP * 2 * 1248;      // 2*96*96 floats

  hipMemsetAsync(part, 0, NP * 2 * 1248 * sizeof(float), stream);
  p1<<<512, 256, 0, stream>>>(x, Wk, Wv, part);
  kB<<<72, 256, 0, stream>>>(part, Wproj, Mt);
  p3<<<512, 256, 0, stream>>>(x, Wq, Mt, out);
}